// Round 15
// baseline (163.318 us; speedup 1.0000x reference)
//
#include <hip/hip_runtime.h>
#include <math.h>

#define TPB 256
#define EPT 16      // elements per thread
#define NN  4096    // row length (fixed by problem)
#define KSEL 410    // K = round(4096 * 0.1)
#define CAP 1024    // candidate list capacity (expected max bin ~95)

typedef float floatx4 __attribute__((ext_vector_type(4)));

// Async global->LDS DMA, 16B/lane. LDS dest is wave-uniform base (HW adds lane*16),
// global src is per-lane [m104/m108]. Issue position is preserved by the compiler
// (void side-effecting intrinsic) — the ONLY load form that provably stays in flight.
__device__ __forceinline__ void dma16(const float* gsrc, float* lds) {
    __builtin_amdgcn_global_load_lds(
        (__attribute__((address_space(1))) void*)(void*)gsrc,
        (__attribute__((address_space(3))) void*)(void*)lds,
        16, 0, 0);
}

template <bool USE_WS>
__global__ __launch_bounds__(TPB)
void skw_main(const float* __restrict__ x, const float* __restrict__ g,
              float* __restrict__ out, float* __restrict__ rowH,
              float* __restrict__ entAcc, float invB)
{
    const int row  = blockIdx.x;
    const int t    = threadIdx.x;
    const int w    = t >> 6;          // wave id 0..3
    const int lane = t & 63;
    const size_t rbase = (size_t)row * NN;

    unsigned bp[EPT / 4];             // value-domain bins, byte-packed

    __shared__ float    stage[2 * NN];   // 32 KB: x in [0,4096), g->s in [4096,8192)
    __shared__ unsigned hist0[256][5];   // bin histogram: 4 slots + 1 pad (stride 5)
    __shared__ unsigned wtot[4];
    __shared__ unsigned wtA[4], wtB[4];
    __shared__ float    fred[8];
    __shared__ unsigned sh_digit, sh_above, sh_cnt, sh_take, sh_eq;
    __shared__ float    sh_thr;

    float*   list = reinterpret_cast<float*>(&hist0[0][0]);  // alias; used after B4 (5120B >= CAP*4)
    floatx4* sx4  = reinterpret_cast<floatx4*>(stage);           // x region, float4 view
    floatx4* ss4  = reinterpret_cast<floatx4*>(stage + NN);      // g/s region, float4 view

    const float* xr = x + rbase;
    const float* gr = g + rbase;
    floatx4*     op = reinterpret_cast<floatx4*>(out + rbase);

    // ---- stage x,g via async DMA: wave w stages EXACTLY the chunks it consumes ----
    // chunk c = q*4 + w holds flat floats [c*256, c*256+256); thread t=(w,lane) consumes
    // flat q*1024 + t*4 = c*256 + lane*4. All deps same-wave => NO barrier, no dbuf.
#pragma unroll
    for (int q = 0; q < 4; ++q) {
        const int c = (q << 2) + w;
        dma16(xr + (c << 8) + (lane << 2), &stage[c << 8]);
        dma16(gr + (c << 8) + (lane << 2), &stage[NN + (c << 8)]);
    }

    // zero bin histogram (+ counter) while DMA is in flight
    unsigned* h0 = &hist0[0][0];
#pragma unroll
    for (int i = 0; i < 5; ++i) h0[t + 256 * i] = 0;
    if (t == 0) sh_cnt = 0;

    // wait for my wave's 8 DMAs (the only outstanding vmem)
    asm volatile("s_waitcnt vmcnt(0)" ::: "memory");

    // ---- keys/bins/entropy from LDS; s = x/10 + g exact (Markstein); s overwrites g ----
    float sZ = 0.f, sZL = 0.f;
#pragma unroll
    for (int q = 0; q < EPT / 4; ++q) {
        floatx4 xx = sx4[(q << 8) + t];
        floatx4 gg = ss4[(q << 8) + t];
        floatx4 so;
        unsigned pk = 0;
#pragma unroll
        for (int jj = 0; jj < 4; ++jj) {
            float xs = xx[jj];
            float l = xs * 0.1f;                  // y0 = RN(x * RN(0.1))
            float e = __expf(l);
            sZ  += e;
            sZL = __builtin_fmaf(e, l, sZL);
            // correctly-rounded x/10: q10 = y0 + (x - 10*y0)*0.1 (x/10 never at f32 midpoint)
            float q10 = __builtin_fmaf(__builtin_fmaf(-10.0f, l, xs), 0.1f, l);
            float s = q10 + gg[jj];
            so[jj] = s;
            int b = (int)__builtin_fmaf(s, 16.0f, 64.0f);   // (s+4)*16, monotone in s
            b = min(max(b, 0), 255);
            pk |= (unsigned)b << (8 * jj);
        }
        ss4[(q << 8) + t] = so;                   // same-thread overwrite; no barrier
        bp[q] = pk;
    }

    // ---- entropy reduce (m = 0 is safe: |x*0.1| < ~0.6) ----
#pragma unroll
    for (int sft = 32; sft >= 1; sft >>= 1) { sZ += __shfl_xor(sZ, sft); sZL += __shfl_xor(sZL, sft); }
    if (lane == 0) { fred[w] = sZ; fred[4 + w] = sZL; }
    __syncthreads();                                   // B1

    if (t == 0) {
        float Z = fred[0] + fred[1] + fred[2] + fred[3];
        float L = fred[4] + fred[5] + fred[6] + fred[7];
        float H = __logf(Z) - L / Z;                   // H = lnZ - E[l]
        if (USE_WS) rowH[row] = H;
        else atomicAdd(entAcc, H * invB);
    }

    // ---- value-bin histogram (near-uniform bins; 4-way slot split; 2-way aliasing free) ----
#pragma unroll
    for (int q = 0; q < EPT / 4; ++q) {
        unsigned pk = bp[q];
#pragma unroll
        for (int jj = 0; jj < 4; ++jj)
            atomicAdd(&hist0[(pk >> (8 * jj)) & 255u][lane & 3], 1u);
    }
    __syncthreads();                                   // B2

    // merge slots + inclusive suffix scan (shfl) to find crossing bin B*
    unsigned v = hist0[t][0] + hist0[t][1] + hist0[t][2] + hist0[t][3];
#pragma unroll
    for (int sft = 1; sft < 64; sft <<= 1) {
        unsigned tmp = __shfl(v, lane + sft);
        v += (lane + sft < 64) ? tmp : 0u;
    }
    if (lane == 0) wtot[w] = v;
    unsigned vnext = __shfl(v, lane + 1);
    __syncthreads();                                   // B3
    unsigned Kr = KSEL;
    {
        unsigned hi = 0;
#pragma unroll
        for (int c = 0; c < 4; ++c) hi += (c > w) ? wtot[c] : 0u;
        unsigned cum     = v + hi;                          // # keys with bin >= t
        unsigned cumNext = ((lane < 63) ? vnext : 0u) + hi; // # keys with bin >  t
        if (cum >= Kr && cumNext < Kr) { sh_digit = (unsigned)t; sh_above = cumNext; }
    }
    __syncthreads();                                   // B4
    const unsigned Bstar = sh_digit;
    Kr -= sh_above;       // 1-based rank of threshold within bin B* (from largest)

    // ---- append candidates (bin == B*) to LDS list (s read back same-thread) ----
#pragma unroll
    for (int q = 0; q < EPT / 4; ++q) {
        unsigned pk = bp[q];
#pragma unroll
        for (int jj = 0; jj < 4; ++jj) {
            if (((pk >> (8 * jj)) & 255u) == Bstar) {
                unsigned p = atomicAdd(&sh_cnt, 1u);
                if (p < CAP) list[p] = stage[NN + (q << 10) + 4 * t + jj];
            }
        }
    }
    __syncthreads();                                   // B5

    // ---- exact rank among the ~25-95 candidates (float compares) ----
    const unsigned M = sh_cnt;
    for (unsigned i = t; i < M; i += TPB) {
        float ki = list[i];
        unsigned gt = 0, eqc = 0;
        for (unsigned j2 = 0; j2 < M; ++j2) {
            float kj = list[j2];                       // broadcast read
            gt  += (kj > ki)  ? 1u : 0u;
            eqc += (kj == ki) ? 1u : 0u;
        }
        if (gt < Kr && Kr <= gt + eqc) { sh_thr = ki; sh_take = Kr - gt; sh_eq = eqc; }
    }
    __syncthreads();                                   // B6
    const float    thr    = sh_thr;    // exact K-th largest s overall
    const unsigned KrTake = sh_take;   // # equal-to-thr to accept
    const unsigned EqTot  = sh_eq;     // # equal-to-thr total

    if (KrTake == EqTot) {
        // ---- FAST PATH (unique threshold, the ~always case): sel = s >= thr ----
#pragma unroll
        for (int q = 0; q < EPT / 4; ++q) {
            floatx4 sq = ss4[(q << 8) + t];
            floatx4 xq = sx4[(q << 8) + t];
            floatx4 o4;
#pragma unroll
            for (int jj = 0; jj < 4; ++jj)
                o4[jj] = (sq[jj] >= thr) ? xq[jj] : 0.0f;
            __builtin_nontemporal_store(o4, &op[(q << 8) + t]);
        }
    } else {
        // ===== degenerate ties: lowest-index-first, column order c = q*1024 + t*4 + jj =====
        unsigned eq[4];
#pragma unroll
        for (int q = 0; q < 4; ++q) {
            floatx4 sq = ss4[(q << 8) + t];
            unsigned e = 0;
#pragma unroll
            for (int jj = 0; jj < 4; ++jj) e += (sq[jj] == thr) ? 1u : 0u;
            eq[q] = e;
        }
        unsigned wA = eq[0] | (eq[1] << 16);
        unsigned wB = eq[2] | (eq[3] << 16);
        unsigned sA = wA, sB = wB;
#pragma unroll
        for (int sft = 1; sft < 64; sft <<= 1) {       // inclusive prefix scan within wave
            unsigned ta = __shfl(sA, lane - sft);
            unsigned tb = __shfl(sB, lane - sft);
            if (lane >= sft) { sA += ta; sB += tb; }
        }
        if (lane == 63) { wtA[w] = sA; wtB[w] = sB; }
        __syncthreads();                               // B7 (block-uniform branch: legal)
        unsigned offA = 0, offB = 0, totA = 0, totB = 0;
#pragma unroll
        for (int c = 0; c < 4; ++c) {
            totA += wtA[c]; totB += wtB[c];
            if (c < w) { offA += wtA[c]; offB += wtB[c]; }
        }
        unsigned exA = offA + sA - wA;                 // exclusive prefix, packed halves
        unsigned exB = offB + sB - wB;
        unsigned tot0 = totA & 0xFFFFu, tot1 = totA >> 16, tot2 = totB & 0xFFFFu;
        unsigned baseq[4] = {0u, tot0, tot0 + tot1, tot0 + tot1 + tot2};
        unsigned exq[4]   = {exA & 0xFFFFu, exA >> 16, exB & 0xFFFFu, exB >> 16};

#pragma unroll
        for (int q = 0; q < EPT / 4; ++q) {
            unsigned pos = baseq[q] + exq[q];          // equals before my first elem of this q
            floatx4 sq = ss4[(q << 8) + t];
            floatx4 xq = sx4[(q << 8) + t];
            floatx4 o4;
#pragma unroll
            for (int jj = 0; jj < 4; ++jj) {
                bool sel;
                if (sq[jj] > thr)        sel = true;
                else if (sq[jj] == thr)  { sel = (pos < KrTake); ++pos; }
                else                     sel = false;
                o4[jj] = sel ? xq[jj] : 0.0f;
            }
            __builtin_nontemporal_store(o4, &op[(q << 8) + t]);
        }
    }
}

__global__ void skw_zero(float* p) { *p = 0.0f; }

// Deterministic fixed-order mean of rowH -> out scalar.
__global__ void skw_reduce(const float* __restrict__ rowH, float* __restrict__ outp, int B)
{
    __shared__ float red[256];
    int t = threadIdx.x;
    float s = 0.f;
    for (int i = t; i < B; i += 256) s += rowH[i];
    red[t] = s; __syncthreads();
    for (int st = 128; st > 0; st >>= 1) { if (t < st) red[t] += red[t + st]; __syncthreads(); }
    if (t == 0) *outp = red[0] / (float)B;
}

extern "C" void kernel_launch(void* const* d_in, const int* in_sizes, int n_in,
                              void* d_out, int out_size, void* d_ws, size_t ws_size,
                              hipStream_t stream)
{
    const float* x = (const float*)d_in[0];
    const float* g = (const float*)d_in[1];
    float* out = (float*)d_out;
    const int BN = in_sizes[0];
    const int B  = BN / NN;
    float* entp = out + (size_t)BN;

    if (ws_size >= (size_t)B * sizeof(float)) {
        float* rowH = (float*)d_ws;
        skw_main<true><<<B, TPB, 0, stream>>>(x, g, out, rowH, nullptr, 0.f);
        skw_reduce<<<1, 256, 0, stream>>>(rowH, entp, B);
    } else {
        skw_zero<<<1, 1, 0, stream>>>(entp);
        skw_main<false><<<B, TPB, 0, stream>>>(x, g, out, nullptr, entp, 1.0f / (float)B);
    }
}